// Round 8
// baseline (165.027 us; speedup 1.0000x reference)
//
#include <hip/hip_runtime.h>

#define MAXT 16
#define DDIM 1024
#define NTHREADS 256
#define WPB (NTHREADS / 64)   // 4 waves = 4 sites per block

// Full wave64 sum via DPP (VALU pipe only, no DS ops). Result broadcast via readlane.
__device__ __forceinline__ float dpp_sum64(float x) {
    int v;
    v = __builtin_amdgcn_update_dpp(0, __float_as_int(x), 0x111, 0xf, 0xf, true);  // row_shr:1
    x += __int_as_float(v);
    v = __builtin_amdgcn_update_dpp(0, __float_as_int(x), 0x112, 0xf, 0xf, true);  // row_shr:2
    x += __int_as_float(v);
    v = __builtin_amdgcn_update_dpp(0, __float_as_int(x), 0x114, 0xf, 0xf, true);  // row_shr:4
    x += __int_as_float(v);
    v = __builtin_amdgcn_update_dpp(0, __float_as_int(x), 0x118, 0xf, 0xf, true);  // row_shr:8
    x += __int_as_float(v);
    v = __builtin_amdgcn_update_dpp(0, __float_as_int(x), 0x142, 0xa, 0xf, false); // row_bcast:15
    x += __int_as_float(v);
    v = __builtin_amdgcn_update_dpp(0, __float_as_int(x), 0x143, 0xc, 0xf, false); // row_bcast:31
    x += __int_as_float(v);
    return __int_as_float(__builtin_amdgcn_readlane(__float_as_int(x), 63));
}

// One wave per site, flash-style online softmax over the depth dim.
// No __syncthreads, no LDS, no cross-wave coupling: waves are fully
// independent streams; TLP (16 waves/CU) hides all memory latency.
__global__ __launch_bounds__(NTHREADS, 4)
void attn_wave_site_kernel(const float* __restrict__ entries,
                           const float* __restrict__ proj,
                           const float* __restrict__ norm_scale,
                           const int* __restrict__ n_active_p,
                           const int* __restrict__ block_idx_p,
                           float* __restrict__ out,
                           int BS)
{
    const int tid   = threadIdx.x;
    const int wave  = tid >> 6;
    const int lane  = tid & 63;
    const int site  = blockIdx.x * WPB + wave;   // BS % WPB == 0
    const int dbase = lane * 4;                  // lane covers d = c*256 + dbase .. +3

    int n_act = *n_active_p;
    n_act = n_act < 1 ? 1 : (n_act > MAXT ? MAXT : n_act);
    int row = *block_idx_p;
    row = row > (MAXT - 1) ? (MAXT - 1) : (row < 0 ? 0 : row);

    // q = proj[row] * norm_scale at this lane's 16 d-elements (cached, tiny)
    float4 q[4];
#pragma unroll
    for (int c = 0; c < 4; ++c) {
        const float4 p  = *reinterpret_cast<const float4*>(proj + (size_t)row * DDIM + c * 256 + dbase);
        const float4 ns = *reinterpret_cast<const float4*>(norm_scale + c * 256 + dbase);
        q[c] = make_float4(p.x * ns.x, p.y * ns.y, p.z * ns.z, p.w * ns.w);
    }

    const size_t tStride = (size_t)BS * DDIM;
    const float* eb = entries + (size_t)site * DDIM + dbase;

    // A/B double-buffered row prefetch (2 rows in flight per wave).
    float4 A[4], B[4];
#pragma unroll
    for (int c = 0; c < 4; ++c)
        A[c] = *reinterpret_cast<const float4*>(eb + c * 256);
    if (1 < n_act) {
#pragma unroll
        for (int c = 0; c < 4; ++c)
            B[c] = *reinterpret_cast<const float4*>(eb + tStride + c * 256);
    }

    float  m    = -3.0e38f;   // running max
    float  ssum = 0.f;        // running sum of exp(l - m)
    float4 acc[4];
#pragma unroll
    for (int c = 0; c < 4; ++c) acc[c] = make_float4(0.f, 0.f, 0.f, 0.f);

#pragma unroll
    for (int tp = 0; tp < MAXT / 2; ++tp) {
        const int t0 = 2 * tp;
        const int t1 = 2 * tp + 1;

        if (t0 < n_act) {          // wave-uniform
            float s = 0.f, d = 0.f;
#pragma unroll
            for (int c = 0; c < 4; ++c) {
                s = fmaf(A[c].x, A[c].x, s); s = fmaf(A[c].y, A[c].y, s);
                s = fmaf(A[c].z, A[c].z, s); s = fmaf(A[c].w, A[c].w, s);
                d = fmaf(q[c].x, A[c].x, d); d = fmaf(q[c].y, A[c].y, d);
                d = fmaf(q[c].z, A[c].z, d); d = fmaf(q[c].w, A[c].w, d);
            }
            s = dpp_sum64(s);
            d = dpp_sum64(d);
            const float l  = d * rsqrtf(s * (1.f / DDIM) + 1e-5f);
            const float mn = fmaxf(m, l);
            const float cs = __expf(m - mn);   // first iter: exp(-huge) = 0
            const float w  = __expf(l - mn);   // always exp(<=0): no overflow
            ssum = fmaf(ssum, cs, w);
            m = mn;
#pragma unroll
            for (int c = 0; c < 4; ++c) {
                acc[c].x = fmaf(acc[c].x, cs, w * A[c].x);
                acc[c].y = fmaf(acc[c].y, cs, w * A[c].y);
                acc[c].z = fmaf(acc[c].z, cs, w * A[c].z);
                acc[c].w = fmaf(acc[c].w, cs, w * A[c].w);
            }
            if (t0 + 2 < n_act) {   // refill A (registers now dead)
#pragma unroll
                for (int c = 0; c < 4; ++c)
                    A[c] = *reinterpret_cast<const float4*>(eb + (size_t)(t0 + 2) * tStride + c * 256);
            }
        }

        if (t1 < n_act) {          // wave-uniform
            float s = 0.f, d = 0.f;
#pragma unroll
            for (int c = 0; c < 4; ++c) {
                s = fmaf(B[c].x, B[c].x, s); s = fmaf(B[c].y, B[c].y, s);
                s = fmaf(B[c].z, B[c].z, s); s = fmaf(B[c].w, B[c].w, s);
                d = fmaf(q[c].x, B[c].x, d); d = fmaf(q[c].y, B[c].y, d);
                d = fmaf(q[c].z, B[c].z, d); d = fmaf(q[c].w, B[c].w, d);
            }
            s = dpp_sum64(s);
            d = dpp_sum64(d);
            const float l  = d * rsqrtf(s * (1.f / DDIM) + 1e-5f);
            const float mn = fmaxf(m, l);
            const float cs = __expf(m - mn);
            const float w  = __expf(l - mn);
            ssum = fmaf(ssum, cs, w);
            m = mn;
#pragma unroll
            for (int c = 0; c < 4; ++c) {
                acc[c].x = fmaf(acc[c].x, cs, w * B[c].x);
                acc[c].y = fmaf(acc[c].y, cs, w * B[c].y);
                acc[c].z = fmaf(acc[c].z, cs, w * B[c].z);
                acc[c].w = fmaf(acc[c].w, cs, w * B[c].w);
            }
            if (t1 + 2 < n_act) {   // refill B
#pragma unroll
                for (int c = 0; c < 4; ++c)
                    B[c] = *reinterpret_cast<const float4*>(eb + (size_t)(t1 + 2) * tStride + c * 256);
            }
        }
    }

    const float inv = 1.f / ssum;
    float* ob = out + (size_t)site * DDIM + dbase;
#pragma unroll
    for (int c = 0; c < 4; ++c) {
        float4 r;
        r.x = acc[c].x * inv;
        r.y = acc[c].y * inv;
        r.z = acc[c].z * inv;
        r.w = acc[c].w * inv;
        *reinterpret_cast<float4*>(ob + c * 256) = r;
    }
}

extern "C" void kernel_launch(void* const* d_in, const int* in_sizes, int n_in,
                              void* d_out, int out_size, void* d_ws, size_t ws_size,
                              hipStream_t stream)
{
    const float* entries = (const float*)d_in[0];
    const float* proj    = (const float*)d_in[1];
    const float* nscale  = (const float*)d_in[2];
    const int*   n_act   = (const int*)d_in[3];
    const int*   bidx    = (const int*)d_in[4];
    float*       out     = (float*)d_out;

    const int BS = out_size / DDIM;   // B*S = 16384
    attn_wave_site_kernel<<<BS / WPB, NTHREADS, 0, stream>>>(entries, proj, nscale,
                                                             n_act, bidx, out, BS);
}